// Round 10
// baseline (789.193 us; speedup 1.0000x reference)
//
#include <hip/hip_runtime.h>
#include <math.h>

// Problem constants
#define SEQ 4096
#define LL  4097           // sequence + CLS
#define HDIM 32
#define NHEAD 8
#define HD 4
#define FFD 2048
#define NLAYER 6
#define EPSLN 1e-5f
#define NCHUNK 16          // split-K chunks over keys 1..4096 (256 keys each)
#define QB 2               // queries per thread in k_attn
#define RT 64              // FFN row tile
#define FS 128             // FFN f-segment width
#define NFS 16             // FFD / FS

#if __has_builtin(__builtin_amdgcn_exp2f)
#define EXP2 __builtin_amdgcn_exp2f
#else
#define EXP2 exp2f
#endif

#define QSCALE 0.7213475204444817f   // 0.5 * log2(e): folds 1/sqrt(HD) and exp->exp2

typedef float v2f __attribute__((ext_vector_type(2)));
#define FMA2(a, b, c) __builtin_elementwise_fma((a), (b), (c))

__device__ __forceinline__ float dot4(float4 a, float4 b) {
  return fmaf(a.w, b.w, fmaf(a.z, b.z, fmaf(a.y, b.y, a.x * b.x)));
}

// partial sums (implicit m=0), coalesced layout:
//   LP[(c*8+h)*LL + q]  : float   denominator partial
//   AP[(c*8+h)*LL + q]  : float4  numerator partial
// K pair-transposed:  KT[((h*2048+p)*8) + d*2 + par]  (keys 1..4096, p=(k-1)>>1)
// V head-contiguous:  VT[((h*4097+k)*4) + d]

__device__ __forceinline__ void store_ktvt(int row, int ch, int t3, float acc,
    float* __restrict__ KT, float* __restrict__ VT) {
  int h = ch >> 2, d = ch & 3;
  if (t3 == 1) {           // K part
    if (row >= 1) {
      int p = (row - 1) >> 1, par = (row - 1) & 1;
      KT[(((size_t)h * 2048 + p) << 3) + d * 2 + par] = acc;
    }
  } else if (t3 == 2) {    // V part
    if (row >= 1) {
      VT[(((size_t)h * 4097 + row) << 2) + d] = acc;
    }
  }
}

// -------- embed (relu(lin)+PE, CLS=-1) fused with layer-0 qkv ---------------
__global__ __launch_bounds__(256) void k_embed_qkv(const float* __restrict__ data,
    const float* __restrict__ lin_w, const float* __restrict__ lin_b,
    float* __restrict__ x, const float* __restrict__ qw,
    const float* __restrict__ qb, float* __restrict__ qkv,
    float* __restrict__ KT, float* __restrict__ VT) {
  __shared__ float xs[8][33];
  int tid = threadIdx.x;
  int r = tid >> 5, ch = tid & 31;
  int row = blockIdx.x * 8 + r;
  bool ok = row < LL;
  float val = 0.f;
  if (ok) {
    if (row == 0) {
      val = -1.0f;
    } else {
      int s = row - 1;
      float ts = data[s * 3 + 0];
      float f0 = data[s * 3 + 1];
      float f1 = data[s * 3 + 2];
      float lin = f0 * lin_w[ch * 2 + 0] + f1 * lin_w[ch * 2 + 1] + lin_b[ch];
      lin = fmaxf(lin, 0.0f);
      int tsi = (int)(ts / 100.0f);
      int j = ch >> 1;
      float aj = (float)(2 * j) * (float)(-0.28782313662425575);
      float divj = (float)exp((double)aj);
      float ang = (float)tsi * divj;
      float pe = (ch & 1) ? cosf(ang) : sinf(ang);
      val = lin + pe;
    }
    x[(size_t)row * HDIM + ch] = val;
  }
  xs[r][ch] = val;
  __syncthreads();
  if (!ok) return;
#pragma unroll
  for (int t3 = 0; t3 < 3; ++t3) {
    int cc = t3 * 32 + ch;
    const float4* wr = (const float4*)(qw + (size_t)cc * HDIM);
    float acc = qb[cc];
#pragma unroll
    for (int k = 0; k < 8; ++k) {
      float4 wv = wr[k];
      acc = fmaf(xs[r][4 * k + 0], wv.x, acc);
      acc = fmaf(xs[r][4 * k + 1], wv.y, acc);
      acc = fmaf(xs[r][4 * k + 2], wv.z, acc);
      acc = fmaf(xs[r][4 * k + 3], wv.w, acc);
    }
    qkv[(size_t)row * 96 + cc] = acc;
    store_ktvt(row, ch, t3, acc, KT, VT);
  }
}

// -------- transpose w2 for all layers: [NL][32][2048] -> [NL][2048][32] -----
__global__ __launch_bounds__(256) void k_w2t(const float* __restrict__ w2,
                                             float* __restrict__ w2t) {
  int l = blockIdx.x >> 4, t = blockIdx.x & 15;   // 6 layers x 16 k-tiles
  __shared__ float tile[32][129];
  int tid = threadIdx.x;
  const float* src = w2 + (size_t)l * 32 * FFD;
#pragma unroll
  for (int p = 0; p < 16; ++p) {
    int idx = p * 256 + tid;
    int ch = idx >> 7, kk = idx & 127;
    tile[ch][kk] = src[(size_t)ch * FFD + t * 128 + kk];
  }
  __syncthreads();
  float* dst = w2t + (size_t)l * FFD * 32;
#pragma unroll
  for (int p = 0; p < 16; ++p) {
    int idx = p * 256 + tid;
    int kk = idx >> 5, ch = idx & 31;
    dst[(size_t)(t * 128 + kk) * 32 + ch] = tile[ch][kk];
  }
}

// ---- attention partials: flat exp2, split-K, LDS-free main loop ------------
__global__ __launch_bounds__(256) void k_attn(const float* __restrict__ qkv,
    const float* __restrict__ KT, const float* __restrict__ VT,
    float* __restrict__ LP, float4* __restrict__ AP) {
  int tid = threadIdx.x;
  int h = blockIdx.y;
  int c = blockIdx.z;
  int kbase = 1 + c * 256;
  size_t base = ((size_t)c * NHEAD + h) * LL;

  if (blockIdx.x == 8) {
    __shared__ float rl[256];
    __shared__ float4 ra[256];
    float4 q = *(const float4*)(qkv + (size_t)4096 * 96 + h * HD);
    q.x *= QSCALE; q.y *= QSCALE; q.z *= QSCALE; q.w *= QSCALE;
    float4 kv = *(const float4*)(qkv + (size_t)(kbase + tid) * 96 + 32 + h * HD);
    float4 vv = *(const float4*)(qkv + (size_t)(kbase + tid) * 96 + 64 + h * HD);
    float p = EXP2(dot4(q, kv));
    rl[tid] = p;
    ra[tid] = make_float4(p * vv.x, p * vv.y, p * vv.z, p * vv.w);
    __syncthreads();
    for (int s = 128; s > 0; s >>= 1) {
      if (tid < s) {
        rl[tid] += rl[tid + s];
        ra[tid].x += ra[tid + s].x;
        ra[tid].y += ra[tid + s].y;
        ra[tid].z += ra[tid + s].z;
        ra[tid].w += ra[tid + s].w;
      }
      __syncthreads();
    }
    if (tid == 0) {
      LP[base + 4096] = rl[0];
      AP[base + 4096] = ra[0];
    }
    return;
  }

  const v2f* KTh = (const v2f*)(KT + (((size_t)h * 2048 + c * 128) << 3));
  const v2f* VTh = (const v2f*)(VT + (((size_t)h * 4097 + kbase) << 2));

  v2f qb2[QB][4];
  v2f l2[QB], a01[QB], a23[QB];
  int q0 = blockIdx.x * 512 + tid;
#pragma unroll
  for (int i = 0; i < QB; ++i) {
    int q = q0 + i * 256;
    float4 t = *(const float4*)(qkv + (size_t)q * 96 + h * HD);
    t.x *= QSCALE; t.y *= QSCALE; t.z *= QSCALE; t.w *= QSCALE;
    qb2[i][0] = (v2f){t.x, t.x};
    qb2[i][1] = (v2f){t.y, t.y};
    qb2[i][2] = (v2f){t.z, t.z};
    qb2[i][3] = (v2f){t.w, t.w};
    l2[i] = (v2f){0.f, 0.f};
    a01[i] = (v2f){0.f, 0.f};
    a23[i] = (v2f){0.f, 0.f};
  }

#pragma unroll 4
  for (int p = 0; p < 128; ++p) {
    v2f kp0 = KTh[4 * p + 0], kp1 = KTh[4 * p + 1];
    v2f kp2 = KTh[4 * p + 2], kp3 = KTh[4 * p + 3];
    v2f va01 = VTh[4 * p + 0], va23 = VTh[4 * p + 1];
    v2f vb01 = VTh[4 * p + 2], vb23 = VTh[4 * p + 3];
#pragma unroll
    for (int i = 0; i < QB; ++i) {
      v2f s2 = qb2[i][0] * kp0;
      s2 = FMA2(qb2[i][1], kp1, s2);
      s2 = FMA2(qb2[i][2], kp2, s2);
      s2 = FMA2(qb2[i][3], kp3, s2);
      v2f pv;
      pv.x = EXP2(s2.x);
      pv.y = EXP2(s2.y);
      l2[i] += pv;
      v2f pa = pv.xx;
      v2f pb = pv.yy;
      a01[i] = FMA2(pa, va01, a01[i]);
      a23[i] = FMA2(pa, va23, a23[i]);
      a01[i] = FMA2(pb, vb01, a01[i]);
      a23[i] = FMA2(pb, vb23, a23[i]);
    }
  }

#pragma unroll
  for (int i = 0; i < QB; ++i) {
    size_t idx = base + q0 + i * 256;
    LP[idx] = l2[i].x + l2[i].y;
    AP[idx] = make_float4(a01[i].x, a01[i].y, a23[i].x, a23[i].y);
  }
}

// ------- fused: sum split-K partials + analytic key-0 + o-proj + LN1 --------
__global__ __launch_bounds__(256) void k_oproj(const float* __restrict__ LP,
    const float4* __restrict__ AP, const float* __restrict__ qkv,
    float* __restrict__ x, const float* __restrict__ ow,
    const float* __restrict__ ob, const float* __restrict__ g,
    const float* __restrict__ bln) {
  int tid = threadIdx.x;
  int r = tid >> 5, ch = tid & 31;
  int row = blockIdx.x * 8 + r;
  __shared__ float os[8][32];
  bool ok = row < LL;
  if (ok) {
    int h = ch >> 2, d = ch & 3;
    float L = 0.f, A = 0.f;
#pragma unroll
    for (int c = 0; c < NCHUNK; ++c) {
      size_t idx = ((size_t)c * NHEAD + h) * LL + row;
      L += LP[idx];
      A += ((const float*)&AP[idx])[d];
    }
    float4 q4 = *(const float4*)(qkv + (size_t)row * 96 + h * HD);
    float4 k04 = *(const float4*)(qkv + 32 + h * HD);
    float p0 = EXP2(QSCALE * dot4(q4, k04));
    L += p0;
    A = fmaf(p0, qkv[64 + h * HD + d], A);
    os[r][ch] = A / L;
  } else {
    os[r][ch] = 0.f;
  }
  __syncthreads();
  float acc = 0.f;
#pragma unroll
  for (int k = 0; k < 32; ++k) acc = fmaf(os[r][k], ow[ch * 32 + k], acc);
  float val = ok ? (x[(size_t)row * HDIM + ch] + acc + ob[ch]) : 0.f;
  float mean = val;
#pragma unroll
  for (int off = 16; off > 0; off >>= 1) mean += __shfl_xor(mean, off, 32);
  mean *= (1.f / 32.f);
  float d2 = val - mean;
  float var = d2 * d2;
#pragma unroll
  for (int off = 16; off > 0; off >>= 1) var += __shfl_xor(var, off, 32);
  var *= (1.f / 32.f);
  float y = d2 / sqrtf(var + EPSLN) * g[ch] + bln[ch];
  if (ok) x[(size_t)row * HDIM + ch] = y;
}

// ---------------- FFN part A v2: weights from global, minimal LDS -----------
// grid (65, 16). LDS: Xs 9.2KB + Fs 35.8KB = 45KB -> 3 blocks/CU.
// phase1: thread (rg=tid>>4, cg=tid&15) -> rows rg*4..+3, cols cg*8..+7;
//         W1 read direct from global (L1-hot, 16KB/seg).
// phase2: thread (kq=tid>>6, r4=(tid>>2)&15, c8=tid&3) -> rows {r4+16i},
//         k-range kq*32..+31; W2T pre-transposed so reads are 1 line/inst.
__global__ __launch_bounds__(256) void k_ffnA(const float* __restrict__ x,
    const float* __restrict__ w1, const float* __restrict__ b1,
    const float* __restrict__ w2t, float* __restrict__ part2) {
  __shared__ float Xs[RT][36];
  __shared__ float Fs[RT][140];
  int tid = threadIdx.x;
  int r0 = blockIdx.x * RT;
  int f0 = blockIdx.y * FS;

#pragma unroll
  for (int p = 0; p < 8; ++p) {
    int idx = p * 256 + tid;
    int r = idx >> 5, k = idx & 31;
    Xs[r][k] = (r0 + r < LL) ? x[(size_t)(r0 + r) * HDIM + k] : 0.f;
  }
  __syncthreads();

  // ---- phase 1 ----
  {
    int rg = tid >> 4, cg = tid & 15;
    const float* w1b = w1 + (size_t)(f0 + cg * 8) * HDIM;
    float acc[4][8];
#pragma unroll
    for (int i = 0; i < 4; ++i)
#pragma unroll
      for (int j = 0; j < 8; ++j) acc[i][j] = 0.f;
#pragma unroll
    for (int k4 = 0; k4 < 8; ++k4) {
      float4 xv0 = *(const float4*)&Xs[rg * 4 + 0][k4 * 4];
      float4 xv1 = *(const float4*)&Xs[rg * 4 + 1][k4 * 4];
      float4 xv2 = *(const float4*)&Xs[rg * 4 + 2][k4 * 4];
      float4 xv3 = *(const float4*)&Xs[rg * 4 + 3][k4 * 4];
#pragma unroll
      for (int j = 0; j < 8; ++j) {
        float4 w = *(const float4*)(w1b + (size_t)j * HDIM + k4 * 4);
        acc[0][j] = fmaf(xv0.x, w.x, fmaf(xv0.y, w.y, fmaf(xv0.z, w.z, fmaf(xv0.w, w.w, acc[0][j]))));
        acc[1][j] = fmaf(xv1.x, w.x, fmaf(xv1.y, w.y, fmaf(xv1.z, w.z, fmaf(xv1.w, w.w, acc[1][j]))));
        acc[2][j] = fmaf(xv2.x, w.x, fmaf(xv2.y, w.y, fmaf(xv2.z, w.z, fmaf(xv2.w, w.w, acc[2][j]))));
        acc[3][j] = fmaf(xv3.x, w.x, fmaf(xv3.y, w.y, fmaf(xv3.z, w.z, fmaf(xv3.w, w.w, acc[3][j]))));
      }
    }
    float4 bv0 = *(const float4*)(b1 + f0 + cg * 8);
    float4 bv1 = *(const float4*)(b1 + f0 + cg * 8 + 4);
#pragma unroll
    for (int i = 0; i < 4; ++i) {
      float4 o0, o1;
      o0.x = fmaxf(acc[i][0] + bv0.x, 0.f);
      o0.y = fmaxf(acc[i][1] + bv0.y, 0.f);
      o0.z = fmaxf(acc[i][2] + bv0.z, 0.f);
      o0.w = fmaxf(acc[i][3] + bv0.w, 0.f);
      o1.x = fmaxf(acc[i][4] + bv1.x, 0.f);
      o1.y = fmaxf(acc[i][5] + bv1.y, 0.f);
      o1.z = fmaxf(acc[i][6] + bv1.z, 0.f);
      o1.w = fmaxf(acc[i][7] + bv1.w, 0.f);
      *(float4*)&Fs[rg * 4 + i][cg * 8] = o0;
      *(float4*)&Fs[rg * 4 + i][cg * 8 + 4] = o1;
    }
  }
  __syncthreads();

  // ---- phase 2 ----
  int kq = tid >> 6, r4 = (tid >> 2) & 15, c8 = tid & 3;
  float a2[4][8];
#pragma unroll
  for (int i = 0; i < 4; ++i)
#pragma unroll
    for (int j = 0; j < 8; ++j) a2[i][j] = 0.f;
  {
    const float* w2b = w2t + (size_t)(f0 + kq * 32) * 32 + c8 * 8;
#pragma unroll
    for (int k4 = 0; k4 < 8; ++k4) {
      int kk = kq * 32 + k4 * 4;
      float4 f0v = *(const float4*)&Fs[r4 + 0][kk];
      float4 f1v = *(const float4*)&Fs[r4 + 16][kk];
      float4 f2v = *(const float4*)&Fs[r4 + 32][kk];
      float4 f3v = *(const float4*)&Fs[r4 + 48][kk];
#pragma unroll
      for (int t = 0; t < 4; ++t) {
        float4 wlo = *(const float4*)(w2b + (size_t)(k4 * 4 + t) * 32);
        float4 whi = *(const float4*)(w2b + (size_t)(k4 * 4 + t) * 32 + 4);
        float fk0 = ((const float*)&f0v)[t];
        float fk1 = ((const float*)&f1v)[t];
        float fk2 = ((const float*)&f2v)[t];
        float fk3 = ((const float*)&f3v)[t];
        a2[0][0] = fmaf(fk0, wlo.x, a2[0][0]); a2[0][1] = fmaf(fk0, wlo.y, a2[0][1]);
        a2[0][2] = fmaf(fk0, wlo.z, a2[0][2]); a2[0][3] = fmaf(fk0, wlo.w, a2[0][3]);
        a2[0][4] = fmaf(fk0, whi.x, a2[0][4]); a2[0][5] = fmaf(fk0, whi.y, a2[0][5]);
        a2[0][6] = fmaf(fk0, whi.z, a2[0][6]); a2[0][7] = fmaf(fk0, whi.w, a2[0][7]);
        a2[1][0] = fmaf(fk1, wlo.x, a2[1][0]); a2[1][1] = fmaf(fk1, wlo.y, a2[1][1]);
        a2[1][2] = fmaf(fk1, wlo.z, a2[1][2]); a2[1][3] = fmaf(fk1, wlo.w, a2[1][3]);
        a2[1][4] = fmaf(fk1, whi.x, a2[1][4]); a2[1][5] = fmaf(fk1, whi.y, a2[1][5]);
        a2[1][6] = fmaf(fk1, whi.z, a2[1][6]); a2[1][7] = fmaf(fk1, whi.w, a2[1][7]);
        a2[2][0] = fmaf(fk2, wlo.x, a2[2][0]); a2[2][1] = fmaf(fk2, wlo.y, a2[2][1]);
        a2[2][2] = fmaf(fk2, wlo.z, a2[2][2]); a2[2][3] = fmaf(fk2, wlo.w, a2[2][3]);
        a2[2][4] = fmaf(fk2, whi.x, a2[2][4]); a2[2][5] = fmaf(fk2, whi.y, a2[2][5]);
        a2[2][6] = fmaf(fk2, whi.z, a2[2][6]); a2[2][7] = fmaf(fk2, whi.w, a2[2][7]);
        a2[3][0] = fmaf(fk3, wlo.x, a2[3][0]); a2[3][1] = fmaf(fk3, wlo.y, a2[3][1]);
        a2[3][2] = fmaf(fk3, wlo.z, a2[3][2]); a2[3][3] = fmaf(fk3, wlo.w, a2[3][3]);
        a2[3][4] = fmaf(fk3, whi.x, a2[3][4]); a2[3][5] = fmaf(fk3, whi.y, a2[3][5]);
        a2[3][6] = fmaf(fk3, whi.z, a2[3][6]); a2[3][7] = fmaf(fk3, whi.w, a2[3][7]);
      }
    }
  }
  // merge 4 k-quarters in LDS (reuse Xs[64][36] cols 0..31)
  for (int q = 0; q < 4; ++q) {
    __syncthreads();
    if (kq == q) {
#pragma unroll
      for (int i = 0; i < 4; ++i)
#pragma unroll
        for (int j = 0; j < 8; ++j) {
          int rr = r4 + 16 * i, cc = c8 * 8 + j;
          if (q == 0) Xs[rr][cc] = a2[i][j];
          else Xs[rr][cc] += a2[i][j];
        }
    }
  }
  __syncthreads();
#pragma unroll
  for (int p = 0; p < 8; ++p) {
    int idx = p * 256 + tid;
    int r = idx >> 5, cc = idx & 31;
    if (r0 + r < LL)
      part2[((size_t)blockIdx.y * LL + r0 + r) * HDIM + cc] = Xs[r][cc];
  }
}

// ------ FFN part B: combine + residual + LN2 + next qkv (+KT/VT) + final ----
__global__ __launch_bounds__(256) void k_ffnB_qkv(float* __restrict__ x,
    const float* __restrict__ part2, const float* __restrict__ b2,
    const float* __restrict__ g, const float* __restrict__ bln,
    const float* __restrict__ qw, const float* __restrict__ qb,
    float* __restrict__ qkv, float* __restrict__ KT, float* __restrict__ VT,
    int do_qkv, const float* __restrict__ cw, const float* __restrict__ cb,
    float* __restrict__ out) {
  __shared__ float xs[8][33];
  int tid = threadIdx.x;
  int r = tid >> 5, ch = tid & 31;
  int row = blockIdx.x * 8 + r;
  bool ok = row < LL;
  float s = 0.f;
  if (ok) {
#pragma unroll
    for (int q = 0; q < NFS; ++q)
      s += part2[((size_t)q * LL + row) * HDIM + ch];
  }
  float val = ok ? (x[(size_t)row * HDIM + ch] + s + b2[ch]) : 0.f;
  float mean = val;
#pragma unroll
  for (int off = 16; off > 0; off >>= 1) mean += __shfl_xor(mean, off, 32);
  mean *= (1.f / 32.f);
  float d = val - mean;
  float var = d * d;
#pragma unroll
  for (int off = 16; off > 0; off >>= 1) var += __shfl_xor(var, off, 32);
  var *= (1.f / 32.f);
  float y = d / sqrtf(var + EPSLN) * g[ch] + bln[ch];
  if (ok) x[(size_t)row * HDIM + ch] = y;
  xs[r][ch] = ok ? y : 0.f;
  __syncthreads();
  if (!do_qkv) {
    if (blockIdx.x == 0 && r == 0) {
      float t = y * cw[ch];
#pragma unroll
      for (int off = 16; off > 0; off >>= 1) t += __shfl_xor(t, off, 32);
      if (ch == 0) {
        float z = t + cb[0];
        out[0] = 1.f / (1.f + expf(-z));
      }
    }
    return;
  }
  if (!ok) return;
#pragma unroll
  for (int t3 = 0; t3 < 3; ++t3) {
    int cc = t3 * 32 + ch;
    const float4* wr = (const float4*)(qw + (size_t)cc * HDIM);
    float acc = qb[cc];
#pragma unroll
    for (int k = 0; k < 8; ++k) {
      float4 wv = wr[k];
      acc = fmaf(xs[r][4 * k + 0], wv.x, acc);
      acc = fmaf(xs[r][4 * k + 1], wv.y, acc);
      acc = fmaf(xs[r][4 * k + 2], wv.z, acc);
      acc = fmaf(xs[r][4 * k + 3], wv.w, acc);
    }
    qkv[(size_t)row * 96 + cc] = acc;
    store_ktvt(row, ch, t3, acc, KT, VT);
  }
}

extern "C" void kernel_launch(void* const* d_in, const int* in_sizes, int n_in,
                              void* d_out, int out_size, void* d_ws, size_t ws_size,
                              hipStream_t stream) {
  const float* data  = (const float*)d_in[0];
  const float* lin_w = (const float*)d_in[1];
  const float* lin_b = (const float*)d_in[2];
  const float* qkv_w = (const float*)d_in[3];
  const float* qkv_b = (const float*)d_in[4];
  const float* out_w = (const float*)d_in[5];
  const float* out_b = (const float*)d_in[6];
  const float* ln1_g = (const float*)d_in[7];
  const float* ln1_b = (const float*)d_in[8];
  const float* ff1_w = (const float*)d_in[9];
  const float* ff1_b = (const float*)d_in[10];
  const float* ff2_w = (const float*)d_in[11];
  const float* ff2_b = (const float*)d_in[12];
  const float* ln2_g = (const float*)d_in[13];
  const float* ln2_b = (const float*)d_in[14];
  const float* cls_w = (const float*)d_in[15];
  const float* cls_b = (const float*)d_in[16];

  float* ws = (float*)d_ws;
  float*  X   = ws;                                  // LL*32
  float*  QKV = X + (size_t)LL * 32;                 // LL*96
  float*  KT  = QKV + (size_t)LL * 96;               // 8*2048*8
  float*  VT  = KT + (size_t)8 * 2048 * 8;           // 8*4097*4
  float4* AP  = (float4*)(VT + (size_t)8 * 4097 * 4);        // NCHUNK*NHEAD*LL
  float*  LP  = (float*)(AP + (size_t)NCHUNK * NHEAD * LL);  // NCHUNK*NHEAD*LL
  float*  W2T = LP + (size_t)NCHUNK * NHEAD * LL;    // NL*FFD*32
  float*  PART2 = (float*)AP;                        // aliased: disjoint lifetimes

  const int NROWB = (LL + 7) / 8;                    // 513

  k_w2t<<<NLAYER * 16, 256, 0, stream>>>(ff2_w, W2T);
  k_embed_qkv<<<NROWB, 256, 0, stream>>>(data, lin_w, lin_b, X,
                                         qkv_w, qkv_b, QKV, KT, VT);
  for (int l = 0; l < NLAYER; ++l) {
    k_attn<<<dim3(9, NHEAD, NCHUNK), 256, 0, stream>>>(QKV, KT, VT, LP, AP);
    k_oproj<<<NROWB, 256, 0, stream>>>(
        LP, AP, QKV, X, out_w + (size_t)l * 32 * 32, out_b + (size_t)l * 32,
        ln1_g + (size_t)l * 32, ln1_b + (size_t)l * 32);
    k_ffnA<<<dim3((LL + RT - 1) / RT, NFS), 256, 0, stream>>>(
        X, ff1_w + (size_t)l * FFD * 32, ff1_b + (size_t)l * FFD,
        W2T + (size_t)l * FFD * 32, PART2);
    int nl = l + 1;
    int do_qkv = (nl < NLAYER) ? 1 : 0;
    const float* qw = qkv_w + (size_t)(do_qkv ? nl : 0) * 96 * 32;
    const float* qb = qkv_b + (size_t)(do_qkv ? nl : 0) * 96;
    k_ffnB_qkv<<<NROWB, 256, 0, stream>>>(
        X, PART2, ff2_b + (size_t)l * 32,
        ln2_g + (size_t)l * 32, ln2_b + (size_t)l * 32,
        qw, qb, QKV, KT, VT, do_qkv, cls_w, cls_b, (float*)d_out);
  }
}

// Round 11
// 557.266 us; speedup vs baseline: 1.4162x; 1.4162x over previous
//
#include <hip/hip_runtime.h>
#include <math.h>

// Problem constants
#define SEQ 4096
#define LL  4097           // sequence + CLS
#define HDIM 32
#define NHEAD 8
#define HD 4
#define FFD 2048
#define NLAYER 6
#define EPSLN 1e-5f
#define NCHUNK 16          // split-K chunks over keys 1..4096 (256 keys each)
#define QB 2               // queries per thread in k_attn
#define RT 64              // FFN row tile
#define FS 128             // FFN f-segment width
#define NFS 16             // FFD / FS

#if __has_builtin(__builtin_amdgcn_exp2f)
#define EXP2 __builtin_amdgcn_exp2f
#else
#define EXP2 exp2f
#endif

#define QSCALE 0.7213475204444817f   // 0.5 * log2(e): folds 1/sqrt(HD) and exp->exp2

typedef float v2f __attribute__((ext_vector_type(2)));
typedef short bf16x8 __attribute__((ext_vector_type(8)));
typedef float f32x4 __attribute__((ext_vector_type(4)));
#define FMA2(a, b, c) __builtin_elementwise_fma((a), (b), (c))

__device__ __forceinline__ float dot4(float4 a, float4 b) {
  return fmaf(a.w, b.w, fmaf(a.z, b.z, fmaf(a.y, b.y, a.x * b.x)));
}

__device__ __forceinline__ unsigned short f2b(float f) {   // fp32 -> bf16 RNE
  unsigned int b = __float_as_uint(f);
  b += 0x7FFFu + ((b >> 16) & 1u);
  return (unsigned short)(b >> 16);
}

// partial sums (implicit m=0), coalesced layout:
//   LP[(c*8+h)*LL + q]  : float   denominator partial
//   AP[(c*8+h)*LL + q]  : float4  numerator partial
// K pair-transposed:  KT[((h*2048+p)*8) + d*2 + par]  (keys 1..4096, p=(k-1)>>1)
// V head-contiguous:  VT[((h*4097+k)*4) + d]

__device__ __forceinline__ void store_ktvt(int row, int ch, int t3, float acc,
    float* __restrict__ KT, float* __restrict__ VT) {
  int h = ch >> 2, d = ch & 3;
  if (t3 == 1) {
    if (row >= 1) {
      int p = (row - 1) >> 1, par = (row - 1) & 1;
      KT[(((size_t)h * 2048 + p) << 3) + d * 2 + par] = acc;
    }
  } else if (t3 == 2) {
    if (row >= 1) {
      VT[(((size_t)h * 4097 + row) << 2) + d] = acc;
    }
  }
}

// -------- convert FFN weights to bf16 once (w1 [f][k], w2 [c][f]) -----------
__global__ __launch_bounds__(256) void k_wcvt(const float* __restrict__ w1,
    const float* __restrict__ w2, unsigned short* __restrict__ w1b,
    unsigned short* __restrict__ w2b) {
  int idx = blockIdx.x * 256 + threadIdx.x;
  const int N = NLAYER * FFD * 32;
  if (idx < N) {
    w1b[idx] = f2b(w1[idx]);
    w2b[idx] = f2b(w2[idx]);
  }
}

// -------- embed (relu(lin)+PE, CLS=-1) fused with layer-0 qkv ---------------
__global__ __launch_bounds__(256) void k_embed_qkv(const float* __restrict__ data,
    const float* __restrict__ lin_w, const float* __restrict__ lin_b,
    float* __restrict__ x, const float* __restrict__ qw,
    const float* __restrict__ qb, float* __restrict__ qkv,
    float* __restrict__ KT, float* __restrict__ VT) {
  __shared__ float xs[8][33];
  int tid = threadIdx.x;
  int r = tid >> 5, ch = tid & 31;
  int row = blockIdx.x * 8 + r;
  bool ok = row < LL;
  float val = 0.f;
  if (ok) {
    if (row == 0) {
      val = -1.0f;
    } else {
      int s = row - 1;
      float ts = data[s * 3 + 0];
      float f0 = data[s * 3 + 1];
      float f1 = data[s * 3 + 2];
      float lin = f0 * lin_w[ch * 2 + 0] + f1 * lin_w[ch * 2 + 1] + lin_b[ch];
      lin = fmaxf(lin, 0.0f);
      int tsi = (int)(ts / 100.0f);
      int j = ch >> 1;
      float aj = (float)(2 * j) * (float)(-0.28782313662425575);
      float divj = (float)exp((double)aj);
      float ang = (float)tsi * divj;
      float pe = (ch & 1) ? cosf(ang) : sinf(ang);
      val = lin + pe;
    }
    x[(size_t)row * HDIM + ch] = val;
  }
  xs[r][ch] = val;
  __syncthreads();
  if (!ok) return;
#pragma unroll
  for (int t3 = 0; t3 < 3; ++t3) {
    int cc = t3 * 32 + ch;
    const float4* wr = (const float4*)(qw + (size_t)cc * HDIM);
    float acc = qb[cc];
#pragma unroll
    for (int k = 0; k < 8; ++k) {
      float4 wv = wr[k];
      acc = fmaf(xs[r][4 * k + 0], wv.x, acc);
      acc = fmaf(xs[r][4 * k + 1], wv.y, acc);
      acc = fmaf(xs[r][4 * k + 2], wv.z, acc);
      acc = fmaf(xs[r][4 * k + 3], wv.w, acc);
    }
    qkv[(size_t)row * 96 + cc] = acc;
    store_ktvt(row, ch, t3, acc, KT, VT);
  }
}

// ---- attention partials: flat exp2, split-K, LDS-free main loop ------------
__global__ __launch_bounds__(256) void k_attn(const float* __restrict__ qkv,
    const float* __restrict__ KT, const float* __restrict__ VT,
    float* __restrict__ LP, float4* __restrict__ AP) {
  int tid = threadIdx.x;
  int h = blockIdx.y;
  int c = blockIdx.z;
  int kbase = 1 + c * 256;
  size_t base = ((size_t)c * NHEAD + h) * LL;

  if (blockIdx.x == 8) {
    __shared__ float rl[256];
    __shared__ float4 ra[256];
    float4 q = *(const float4*)(qkv + (size_t)4096 * 96 + h * HD);
    q.x *= QSCALE; q.y *= QSCALE; q.z *= QSCALE; q.w *= QSCALE;
    float4 kv = *(const float4*)(qkv + (size_t)(kbase + tid) * 96 + 32 + h * HD);
    float4 vv = *(const float4*)(qkv + (size_t)(kbase + tid) * 96 + 64 + h * HD);
    float p = EXP2(dot4(q, kv));
    rl[tid] = p;
    ra[tid] = make_float4(p * vv.x, p * vv.y, p * vv.z, p * vv.w);
    __syncthreads();
    for (int s = 128; s > 0; s >>= 1) {
      if (tid < s) {
        rl[tid] += rl[tid + s];
        ra[tid].x += ra[tid + s].x;
        ra[tid].y += ra[tid + s].y;
        ra[tid].z += ra[tid + s].z;
        ra[tid].w += ra[tid + s].w;
      }
      __syncthreads();
    }
    if (tid == 0) {
      LP[base + 4096] = rl[0];
      AP[base + 4096] = ra[0];
    }
    return;
  }

  const v2f* KTh = (const v2f*)(KT + (((size_t)h * 2048 + c * 128) << 3));
  const v2f* VTh = (const v2f*)(VT + (((size_t)h * 4097 + kbase) << 2));

  v2f qb2[QB][4];
  v2f l2[QB], a01[QB], a23[QB];
  int q0 = blockIdx.x * 512 + tid;
#pragma unroll
  for (int i = 0; i < QB; ++i) {
    int q = q0 + i * 256;
    float4 t = *(const float4*)(qkv + (size_t)q * 96 + h * HD);
    t.x *= QSCALE; t.y *= QSCALE; t.z *= QSCALE; t.w *= QSCALE;
    qb2[i][0] = (v2f){t.x, t.x};
    qb2[i][1] = (v2f){t.y, t.y};
    qb2[i][2] = (v2f){t.z, t.z};
    qb2[i][3] = (v2f){t.w, t.w};
    l2[i] = (v2f){0.f, 0.f};
    a01[i] = (v2f){0.f, 0.f};
    a23[i] = (v2f){0.f, 0.f};
  }

#pragma unroll 4
  for (int p = 0; p < 128; ++p) {
    v2f kp0 = KTh[4 * p + 0], kp1 = KTh[4 * p + 1];
    v2f kp2 = KTh[4 * p + 2], kp3 = KTh[4 * p + 3];
    v2f va01 = VTh[4 * p + 0], va23 = VTh[4 * p + 1];
    v2f vb01 = VTh[4 * p + 2], vb23 = VTh[4 * p + 3];
#pragma unroll
    for (int i = 0; i < QB; ++i) {
      v2f s2 = qb2[i][0] * kp0;
      s2 = FMA2(qb2[i][1], kp1, s2);
      s2 = FMA2(qb2[i][2], kp2, s2);
      s2 = FMA2(qb2[i][3], kp3, s2);
      v2f pv;
      pv.x = EXP2(s2.x);
      pv.y = EXP2(s2.y);
      l2[i] += pv;
      v2f pa = pv.xx;
      v2f pb = pv.yy;
      a01[i] = FMA2(pa, va01, a01[i]);
      a23[i] = FMA2(pa, va23, a23[i]);
      a01[i] = FMA2(pb, vb01, a01[i]);
      a23[i] = FMA2(pb, vb23, a23[i]);
    }
  }

#pragma unroll
  for (int i = 0; i < QB; ++i) {
    size_t idx = base + q0 + i * 256;
    LP[idx] = l2[i].x + l2[i].y;
    AP[idx] = make_float4(a01[i].x, a01[i].y, a23[i].x, a23[i].y);
  }
}

// ------- fused: sum split-K partials + analytic key-0 + o-proj + LN1 --------
__global__ __launch_bounds__(256) void k_oproj(const float* __restrict__ LP,
    const float4* __restrict__ AP, const float* __restrict__ qkv,
    float* __restrict__ x, const float* __restrict__ ow,
    const float* __restrict__ ob, const float* __restrict__ g,
    const float* __restrict__ bln) {
  int tid = threadIdx.x;
  int r = tid >> 5, ch = tid & 31;
  int row = blockIdx.x * 8 + r;
  __shared__ float os[8][32];
  bool ok = row < LL;
  if (ok) {
    int h = ch >> 2, d = ch & 3;
    float L = 0.f, A = 0.f;
#pragma unroll
    for (int c = 0; c < NCHUNK; ++c) {
      size_t idx = ((size_t)c * NHEAD + h) * LL + row;
      L += LP[idx];
      A += ((const float*)&AP[idx])[d];
    }
    float4 q4 = *(const float4*)(qkv + (size_t)row * 96 + h * HD);
    float4 k04 = *(const float4*)(qkv + 32 + h * HD);
    float p0 = EXP2(QSCALE * dot4(q4, k04));
    L += p0;
    A = fmaf(p0, qkv[64 + h * HD + d], A);
    os[r][ch] = A / L;
  } else {
    os[r][ch] = 0.f;
  }
  __syncthreads();
  float acc = 0.f;
#pragma unroll
  for (int k = 0; k < 32; ++k) acc = fmaf(os[r][k], ow[ch * 32 + k], acc);
  float val = ok ? (x[(size_t)row * HDIM + ch] + acc + ob[ch]) : 0.f;
  float mean = val;
#pragma unroll
  for (int off = 16; off > 0; off >>= 1) mean += __shfl_xor(mean, off, 32);
  mean *= (1.f / 32.f);
  float d2 = val - mean;
  float var = d2 * d2;
#pragma unroll
  for (int off = 16; off > 0; off >>= 1) var += __shfl_xor(var, off, 32);
  var *= (1.f / 32.f);
  float y = d2 / sqrtf(var + EPSLN) * g[ch] + bln[ch];
  if (ok) x[(size_t)row * HDIM + ch] = y;
}

// ---------------- FFN part A via MFMA bf16 ----------------------------------
// grid (65, 16), 256 thr = 4 waves. Per block: rows r0..r0+63, f-cols f0..+127.
// GEMM1: f = relu(x[64,32] @ w1seg^T)  -- one 16x16x32 mfma per (wave,ntile).
// f -> LDS bf16 (C-layout -> A-layout relayout), GEMM2: partial = f @ w2seg^T.
// Layouts (m89/m91/m120): A: m=lane&15, k=(lane>>4)*8+j; B: n=lane&15, same k;
// C/D: col=lane&15, row=(lane>>4)*4+reg.
__global__ __launch_bounds__(256) void k_ffnA(const float* __restrict__ x,
    const unsigned short* __restrict__ w1b, const float* __restrict__ b1,
    const unsigned short* __restrict__ w2b, float* __restrict__ part2) {
  __shared__ unsigned short Xsb[RT * 40];    // [row][k] bf16, stride 40
  __shared__ unsigned short Fsb[RT * 136];   // [row][f_local] bf16, stride 136
  int tid = threadIdx.x;
  int r0 = blockIdx.x * RT;
  int f0 = blockIdx.y * FS;
  int wave = tid >> 6, lane = tid & 63;
  int l16 = lane & 15, quad = lane >> 4;
  int m0 = wave * 16;

  // stage x tile -> bf16 LDS
#pragma unroll
  for (int p = 0; p < 8; ++p) {
    int idx = p * 256 + tid;
    int r = idx >> 5, k = idx & 31;
    float v = (r0 + r < LL) ? x[(size_t)(r0 + r) * HDIM + k] : 0.f;
    Xsb[r * 40 + k] = f2b(v);
  }
  __syncthreads();

  // ---- GEMM1: 8 ntiles of 16 f-cols ----
  bf16x8 a1 = *(const bf16x8*)&Xsb[(m0 + l16) * 40 + quad * 8];
  f32x4 c1[8];
#pragma unroll
  for (int t = 0; t < 8; ++t) {
    bf16x8 b =
        *(const bf16x8*)&w1b[(size_t)(f0 + t * 16 + l16) * 32 + quad * 8];
    f32x4 z = {0.f, 0.f, 0.f, 0.f};
    c1[t] = __builtin_amdgcn_mfma_f32_16x16x32_bf16(a1, b, z, 0, 0, 0);
  }
  // bias + relu + store to Fsb (C-layout scatter)
#pragma unroll
  for (int t = 0; t < 8; ++t) {
    float bb = b1[f0 + t * 16 + l16];
#pragma unroll
    for (int reg = 0; reg < 4; ++reg) {
      float v = fmaxf(c1[t][reg] + bb, 0.f);
      int rrow = m0 + quad * 4 + reg;
      Fsb[rrow * 136 + t * 16 + l16] = f2b(v);
    }
  }
  __syncthreads();

  // ---- GEMM2: out[64][32] partial = f[64][128] @ w2seg^T ----
  f32x4 acc[2] = {{0.f, 0.f, 0.f, 0.f}, {0.f, 0.f, 0.f, 0.f}};
#pragma unroll
  for (int kt = 0; kt < 4; ++kt) {
    bf16x8 a2 = *(const bf16x8*)&Fsb[(m0 + l16) * 136 + kt * 32 + quad * 8];
#pragma unroll
    for (int u = 0; u < 2; ++u) {
      bf16x8 b =
          *(const bf16x8*)&w2b[(size_t)(u * 16 + l16) * FFD + f0 + kt * 32 + quad * 8];
      acc[u] = __builtin_amdgcn_mfma_f32_16x16x32_bf16(a2, b, acc[u], 0, 0, 0);
    }
  }
  // epilogue: D row = m0+quad*4+reg, col = u*16+l16
#pragma unroll
  for (int u = 0; u < 2; ++u) {
#pragma unroll
    for (int reg = 0; reg < 4; ++reg) {
      int rrow = r0 + m0 + quad * 4 + reg;
      if (rrow < LL)
        part2[((size_t)blockIdx.y * LL + rrow) * HDIM + u * 16 + l16] =
            acc[u][reg];
    }
  }
}

// ------ FFN part B: combine + residual + LN2 + next qkv (+KT/VT) + final ----
__global__ __launch_bounds__(256) void k_ffnB_qkv(float* __restrict__ x,
    const float* __restrict__ part2, const float* __restrict__ b2,
    const float* __restrict__ g, const float* __restrict__ bln,
    const float* __restrict__ qw, const float* __restrict__ qb,
    float* __restrict__ qkv, float* __restrict__ KT, float* __restrict__ VT,
    int do_qkv, const float* __restrict__ cw, const float* __restrict__ cb,
    float* __restrict__ out) {
  __shared__ float xs[8][33];
  int tid = threadIdx.x;
  int r = tid >> 5, ch = tid & 31;
  int row = blockIdx.x * 8 + r;
  bool ok = row < LL;
  float s = 0.f;
  if (ok) {
#pragma unroll
    for (int q = 0; q < NFS; ++q)
      s += part2[((size_t)q * LL + row) * HDIM + ch];
  }
  float val = ok ? (x[(size_t)row * HDIM + ch] + s + b2[ch]) : 0.f;
  float mean = val;
#pragma unroll
  for (int off = 16; off > 0; off >>= 1) mean += __shfl_xor(mean, off, 32);
  mean *= (1.f / 32.f);
  float d = val - mean;
  float var = d * d;
#pragma unroll
  for (int off = 16; off > 0; off >>= 1) var += __shfl_xor(var, off, 32);
  var *= (1.f / 32.f);
  float y = d / sqrtf(var + EPSLN) * g[ch] + bln[ch];
  if (ok) x[(size_t)row * HDIM + ch] = y;
  xs[r][ch] = ok ? y : 0.f;
  __syncthreads();
  if (!do_qkv) {
    if (blockIdx.x == 0 && r == 0) {
      float t = y * cw[ch];
#pragma unroll
      for (int off = 16; off > 0; off >>= 1) t += __shfl_xor(t, off, 32);
      if (ch == 0) {
        float z = t + cb[0];
        out[0] = 1.f / (1.f + expf(-z));
      }
    }
    return;
  }
  if (!ok) return;
#pragma unroll
  for (int t3 = 0; t3 < 3; ++t3) {
    int cc = t3 * 32 + ch;
    const float4* wr = (const float4*)(qw + (size_t)cc * HDIM);
    float acc = qb[cc];
#pragma unroll
    for (int k = 0; k < 8; ++k) {
      float4 wv = wr[k];
      acc = fmaf(xs[r][4 * k + 0], wv.x, acc);
      acc = fmaf(xs[r][4 * k + 1], wv.y, acc);
      acc = fmaf(xs[r][4 * k + 2], wv.z, acc);
      acc = fmaf(xs[r][4 * k + 3], wv.w, acc);
    }
    qkv[(size_t)row * 96 + cc] = acc;
    store_ktvt(row, ch, t3, acc, KT, VT);
  }
}

extern "C" void kernel_launch(void* const* d_in, const int* in_sizes, int n_in,
                              void* d_out, int out_size, void* d_ws, size_t ws_size,
                              hipStream_t stream) {
  const float* data  = (const float*)d_in[0];
  const float* lin_w = (const float*)d_in[1];
  const float* lin_b = (const float*)d_in[2];
  const float* qkv_w = (const float*)d_in[3];
  const float* qkv_b = (const float*)d_in[4];
  const float* out_w = (const float*)d_in[5];
  const float* out_b = (const float*)d_in[6];
  const float* ln1_g = (const float*)d_in[7];
  const float* ln1_b = (const float*)d_in[8];
  const float* ff1_w = (const float*)d_in[9];
  const float* ff1_b = (const float*)d_in[10];
  const float* ff2_w = (const float*)d_in[11];
  const float* ff2_b = (const float*)d_in[12];
  const float* ln2_g = (const float*)d_in[13];
  const float* ln2_b = (const float*)d_in[14];
  const float* cls_w = (const float*)d_in[15];
  const float* cls_b = (const float*)d_in[16];

  float* ws = (float*)d_ws;
  float*  X   = ws;                                  // LL*32
  float*  QKV = X + (size_t)LL * 32;                 // LL*96
  float*  KT  = QKV + (size_t)LL * 96;               // 8*2048*8
  float*  VT  = KT + (size_t)8 * 2048 * 8;           // 8*4097*4
  float4* AP  = (float4*)(VT + (size_t)8 * 4097 * 4);        // NCHUNK*NHEAD*LL
  float*  LP  = (float*)(AP + (size_t)NCHUNK * NHEAD * LL);  // NCHUNK*NHEAD*LL
  unsigned short* W1B = (unsigned short*)(LP + (size_t)NCHUNK * NHEAD * LL);
  unsigned short* W2B = W1B + (size_t)NLAYER * FFD * 32;
  float*  PART2 = (float*)AP;                        // aliased: disjoint lifetimes

  const int NROWB = (LL + 7) / 8;                    // 513
  const int NW = NLAYER * FFD * 32;                  // 393216

  k_wcvt<<<(NW + 255) / 256, 256, 0, stream>>>(ff1_w, ff2_w, W1B, W2B);
  k_embed_qkv<<<NROWB, 256, 0, stream>>>(data, lin_w, lin_b, X,
                                         qkv_w, qkv_b, QKV, KT, VT);
  for (int l = 0; l < NLAYER; ++l) {
    k_attn<<<dim3(9, NHEAD, NCHUNK), 256, 0, stream>>>(QKV, KT, VT, LP, AP);
    k_oproj<<<NROWB, 256, 0, stream>>>(
        LP, AP, QKV, X, out_w + (size_t)l * 32 * 32, out_b + (size_t)l * 32,
        ln1_g + (size_t)l * 32, ln1_b + (size_t)l * 32);
    k_ffnA<<<dim3((LL + RT - 1) / RT, NFS), 256, 0, stream>>>(
        X, W1B + (size_t)l * FFD * 32, ff1_b + (size_t)l * FFD,
        W2B + (size_t)l * FFD * 32, PART2);
    int nl = l + 1;
    int do_qkv = (nl < NLAYER) ? 1 : 0;
    const float* qw = qkv_w + (size_t)(do_qkv ? nl : 0) * 96 * 32;
    const float* qb = qkv_b + (size_t)(do_qkv ? nl : 0) * 96;
    k_ffnB_qkv<<<NROWB, 256, 0, stream>>>(
        X, PART2, ff2_b + (size_t)l * 32,
        ln2_g + (size_t)l * 32, ln2_b + (size_t)l * 32,
        qw, qb, QKV, KT, VT, do_qkv, cls_w, cls_b, (float*)d_out);
  }
}

// Round 12
// 505.535 us; speedup vs baseline: 1.5611x; 1.1023x over previous
//
#include <hip/hip_runtime.h>
#include <hip/hip_bf16.h>
#include <math.h>

// Problem constants
#define SEQ 4096
#define LL  4097           // sequence + CLS
#define HDIM 32
#define NHEAD 8
#define HD 4
#define FFD 2048
#define NLAYER 6
#define EPSLN 1e-5f
#define NCHUNK 16          // split-K chunks over keys (256 keys each, last 288)
#define KPAD 4128          // keys 0..4096 padded to 129*32
#define QROWS 4224         // 33 blocks * 128 queries
#define RT 64              // FFN row tile
#define FS 128             // FFN f-segment width
#define NFS 16             // FFD / FS

#if __has_builtin(__builtin_amdgcn_exp2f)
#define EXP2 __builtin_amdgcn_exp2f
#else
#define EXP2 exp2f
#endif

#define QSCALE 0.7213475204444817f   // 0.5 * log2(e)

typedef short bf16x8 __attribute__((ext_vector_type(8)));
typedef float f32x4 __attribute__((ext_vector_type(4)));

__device__ __forceinline__ unsigned short f2b(float f) {   // fp32 -> bf16 RNE
  unsigned int b = __float_as_uint(f);
  b += 0x7FFFu + ((b >> 16) & 1u);
  return (unsigned short)(b >> 16);
}

__device__ __forceinline__ unsigned int pk_bf16(float a, float b) {
  __hip_bfloat162 h = __float22bfloat162_rn(make_float2(a, b));
  return *(unsigned int*)&h;
}

// Buffers:
//  Qb  [QROWS][32]  bf16, pre-scaled by QSCALE (pad rows zero)
//  KB  [8][KPAD][32] bf16, per-head zero-masked K (only dims h*4..h*4+3 set)
//  VBt [8][16][KPAD] bf16, rows 0..3 = V dims (permuted key order), row 4 =
//      validity ones, rows 5..15 = 0.  Key permutation within 32-blocks:
//      pos = ((w&15)<<1) | (w>>4)  so (t,l16) C-layout pairs pack adjacently.
//  LP[(c*8+h)*LL+q] float, AP[(c*8+h)*LL+q] float4 — split-K partials.

// ---------------- per-call init: zero masked buffers, set validity ones -----
__global__ __launch_bounds__(256) void k_init(unsigned short* __restrict__ Qb,
    unsigned short* __restrict__ KB, unsigned short* __restrict__ VBt) {
  const int NQ = QROWS * 32;
  const int NK = 8 * KPAD * 32;
  const int NV = 8 * 16 * KPAD;
  int idx = blockIdx.x * 256 + threadIdx.x;
  if (idx < NQ) Qb[idx] = 0;
  if (idx < NK) KB[idx] = 0;
  if (idx < NV) {
    int i = idx % KPAD;
    int d = (idx / KPAD) & 15;
    unsigned short v = 0;
    if (d == 4) {
      int key = (i & ~31) + ((i & 1) << 4) + ((i & 31) >> 1);
      if (key <= 4096) v = 0x3F80;   // bf16 1.0
    }
    VBt[idx] = v;
  }
}

__device__ __forceinline__ void store_qkv_bf16(int row, int ch, int t3,
    float acc, unsigned short* __restrict__ Qb, unsigned short* __restrict__ KB,
    unsigned short* __restrict__ VBt) {
  int h = ch >> 2, d = ch & 3;
  if (t3 == 0) {
    Qb[(size_t)row * 32 + ch] = f2b(QSCALE * acc);
  } else if (t3 == 1) {
    KB[((size_t)h * KPAD + row) * 32 + ch] = f2b(acc);
  } else {
    int w = row & 31;
    int pos = ((w & 15) << 1) | (w >> 4);
    VBt[((size_t)h * 16 + d) * KPAD + (row & ~31) + pos] = f2b(acc);
  }
}

// -------- convert FFN weights to bf16 once (w1 [f][k], w2 [c][f]) -----------
__global__ __launch_bounds__(256) void k_wcvt(const float* __restrict__ w1,
    const float* __restrict__ w2, unsigned short* __restrict__ w1b,
    unsigned short* __restrict__ w2b) {
  int idx = blockIdx.x * 256 + threadIdx.x;
  const int N = NLAYER * FFD * 32;
  if (idx < N) {
    w1b[idx] = f2b(w1[idx]);
    w2b[idx] = f2b(w2[idx]);
  }
}

// -------- embed (relu(lin)+PE, CLS=-1) fused with layer-0 qkv ---------------
__global__ __launch_bounds__(256) void k_embed_qkv(const float* __restrict__ data,
    const float* __restrict__ lin_w, const float* __restrict__ lin_b,
    float* __restrict__ x, const float* __restrict__ qw,
    const float* __restrict__ qb, unsigned short* __restrict__ Qb,
    unsigned short* __restrict__ KB, unsigned short* __restrict__ VBt) {
  __shared__ float xs[8][33];
  int tid = threadIdx.x;
  int r = tid >> 5, ch = tid & 31;
  int row = blockIdx.x * 8 + r;
  bool ok = row < LL;
  float val = 0.f;
  if (ok) {
    if (row == 0) {
      val = -1.0f;
    } else {
      int s = row - 1;
      float ts = data[s * 3 + 0];
      float f0 = data[s * 3 + 1];
      float f1 = data[s * 3 + 2];
      float lin = f0 * lin_w[ch * 2 + 0] + f1 * lin_w[ch * 2 + 1] + lin_b[ch];
      lin = fmaxf(lin, 0.0f);
      int tsi = (int)(ts / 100.0f);
      int j = ch >> 1;
      float aj = (float)(2 * j) * (float)(-0.28782313662425575);
      float divj = (float)exp((double)aj);
      float ang = (float)tsi * divj;
      float pe = (ch & 1) ? cosf(ang) : sinf(ang);
      val = lin + pe;
    }
    x[(size_t)row * HDIM + ch] = val;
  }
  xs[r][ch] = val;
  __syncthreads();
  if (!ok) return;
#pragma unroll
  for (int t3 = 0; t3 < 3; ++t3) {
    int cc = t3 * 32 + ch;
    const float4* wr = (const float4*)(qw + (size_t)cc * HDIM);
    float acc = qb[cc];
#pragma unroll
    for (int k = 0; k < 8; ++k) {
      float4 wv = wr[k];
      acc = fmaf(xs[r][4 * k + 0], wv.x, acc);
      acc = fmaf(xs[r][4 * k + 1], wv.y, acc);
      acc = fmaf(xs[r][4 * k + 2], wv.z, acc);
      acc = fmaf(xs[r][4 * k + 3], wv.w, acc);
    }
    store_qkv_bf16(row, ch, t3, acc, Qb, KB, VBt);
  }
}

// ---- attention via MFMA: scores (per-head masked-K), exp2, PV+denominator --
// grid (33, NHEAD, NCHUNK). Block = 4 waves; wave owns 2 q-tiles (32 queries).
// chunk c: keys c*256 .. +255 (c==15: +287, includes key 4096 + zero pads).
// Score mfma: A=Qb row (full 32 dims), B=KB[h] (zero-masked) -> S[16q][16k].
// P=exp2(S) -> bf16 pairs -> wave-private LDS (permuted cols) -> A of PV mfma.
// PV mfma: B=VBt[h] rows {v0..v3, ones} -> C[16q][n]: n=0..3 numer, n=4 denom.
__global__ __launch_bounds__(256) void k_attn(
    const unsigned short* __restrict__ Qb, const unsigned short* __restrict__ KB,
    const unsigned short* __restrict__ VBt, float* __restrict__ LP,
    float* __restrict__ APf) {
  __shared__ unsigned short Pt[4][2][16 * 40];
  int tid = threadIdx.x;
  int wave = tid >> 6, lane = tid & 63;
  int l16 = lane & 15, quad = lane >> 4;
  int h = blockIdx.y, c = blockIdx.z;
  int q0 = (blockIdx.x * 4 + wave) * 32;
  int kb0 = c * 256;
  int nkb = (c == NCHUNK - 1) ? 9 : 8;

  const unsigned short* KBh = KB + (size_t)h * KPAD * 32;
  const unsigned short* VBh = VBt + (size_t)h * 16 * KPAD;
  unsigned short* Pt0 = &Pt[wave][0][0];
  unsigned short* Pt1 = &Pt[wave][1][0];

  bf16x8 aq0 = *(const bf16x8*)&Qb[(size_t)(q0 + l16) * 32 + quad * 8];
  bf16x8 aq1 = *(const bf16x8*)&Qb[(size_t)(q0 + 16 + l16) * 32 + quad * 8];

  f32x4 accA = {0.f, 0.f, 0.f, 0.f};
  f32x4 accB = {0.f, 0.f, 0.f, 0.f};

  for (int kb = 0; kb < nkb; ++kb) {
    int k0 = kb0 + kb * 32;
    bf16x8 bk0 = *(const bf16x8*)&KBh[(size_t)(k0 + l16) * 32 + quad * 8];
    bf16x8 bk1 = *(const bf16x8*)&KBh[(size_t)(k0 + 16 + l16) * 32 + quad * 8];
    f32x4 z = {0.f, 0.f, 0.f, 0.f};
    f32x4 s00 = __builtin_amdgcn_mfma_f32_16x16x32_bf16(aq0, bk0, z, 0, 0, 0);
    f32x4 s01 = __builtin_amdgcn_mfma_f32_16x16x32_bf16(aq0, bk1, z, 0, 0, 0);
    f32x4 s10 = __builtin_amdgcn_mfma_f32_16x16x32_bf16(aq1, bk0, z, 0, 0, 0);
    f32x4 s11 = __builtin_amdgcn_mfma_f32_16x16x32_bf16(aq1, bk1, z, 0, 0, 0);
#pragma unroll
    for (int reg = 0; reg < 4; ++reg) {
      int row = quad * 4 + reg;
      *(unsigned int*)&Pt0[row * 40 + l16 * 2] =
          pk_bf16(EXP2(s00[reg]), EXP2(s01[reg]));
      *(unsigned int*)&Pt1[row * 40 + l16 * 2] =
          pk_bf16(EXP2(s10[reg]), EXP2(s11[reg]));
    }
    // wave-private LDS transpose (lockstep wave: no barrier needed)
    bf16x8 a2q0 = *(const bf16x8*)&Pt0[l16 * 40 + quad * 8];
    bf16x8 a2q1 = *(const bf16x8*)&Pt1[l16 * 40 + quad * 8];
    bf16x8 bv = *(const bf16x8*)&VBh[(size_t)l16 * KPAD + k0 + quad * 8];
    accA = __builtin_amdgcn_mfma_f32_16x16x32_bf16(a2q0, bv, accA, 0, 0, 0);
    accB = __builtin_amdgcn_mfma_f32_16x16x32_bf16(a2q1, bv, accB, 0, 0, 0);
  }

  size_t base = ((size_t)c * NHEAD + h) * LL;
#pragma unroll
  for (int reg = 0; reg < 4; ++reg) {
    int q = q0 + quad * 4 + reg;
    int q2 = q + 16;
    if (l16 < 4) {
      if (q < LL) APf[(base + q) * 4 + l16] = accA[reg];
      if (q2 < LL) APf[(base + q2) * 4 + l16] = accB[reg];
    } else if (l16 == 4) {
      if (q < LL) LP[base + q] = accA[reg];
      if (q2 < LL) LP[base + q2] = accB[reg];
    }
  }
}

// ------- fused: sum split-K partials + o-proj + residual + LN1 --------------
__global__ __launch_bounds__(256) void k_oproj(const float* __restrict__ LP,
    const float4* __restrict__ AP, float* __restrict__ x,
    const float* __restrict__ ow, const float* __restrict__ ob,
    const float* __restrict__ g, const float* __restrict__ bln) {
  int tid = threadIdx.x;
  int r = tid >> 5, ch = tid & 31;
  int row = blockIdx.x * 8 + r;
  __shared__ float os[8][32];
  bool ok = row < LL;
  if (ok) {
    int h = ch >> 2, d = ch & 3;
    float L = 0.f, A = 0.f;
#pragma unroll
    for (int c = 0; c < NCHUNK; ++c) {
      size_t idx = ((size_t)c * NHEAD + h) * LL + row;
      L += LP[idx];
      A += ((const float*)&AP[idx])[d];
    }
    os[r][ch] = A / L;
  } else {
    os[r][ch] = 0.f;
  }
  __syncthreads();
  float acc = 0.f;
#pragma unroll
  for (int k = 0; k < 32; ++k) acc = fmaf(os[r][k], ow[ch * 32 + k], acc);
  float val = ok ? (x[(size_t)row * HDIM + ch] + acc + ob[ch]) : 0.f;
  float mean = val;
#pragma unroll
  for (int off = 16; off > 0; off >>= 1) mean += __shfl_xor(mean, off, 32);
  mean *= (1.f / 32.f);
  float d2 = val - mean;
  float var = d2 * d2;
#pragma unroll
  for (int off = 16; off > 0; off >>= 1) var += __shfl_xor(var, off, 32);
  var *= (1.f / 32.f);
  float y = d2 / sqrtf(var + EPSLN) * g[ch] + bln[ch];
  if (ok) x[(size_t)row * HDIM + ch] = y;
}

// ---------------- FFN part A via MFMA bf16 ----------------------------------
__global__ __launch_bounds__(256) void k_ffnA(const float* __restrict__ x,
    const unsigned short* __restrict__ w1b, const float* __restrict__ b1,
    const unsigned short* __restrict__ w2b, float* __restrict__ part2) {
  __shared__ unsigned short Xsb[RT * 40];
  __shared__ unsigned short Fsb[RT * 136];
  int tid = threadIdx.x;
  int r0 = blockIdx.x * RT;
  int f0 = blockIdx.y * FS;
  int wave = tid >> 6, lane = tid & 63;
  int l16 = lane & 15, quad = lane >> 4;
  int m0 = wave * 16;

#pragma unroll
  for (int p = 0; p < 8; ++p) {
    int idx = p * 256 + tid;
    int r = idx >> 5, k = idx & 31;
    float v = (r0 + r < LL) ? x[(size_t)(r0 + r) * HDIM + k] : 0.f;
    Xsb[r * 40 + k] = f2b(v);
  }
  __syncthreads();

  bf16x8 a1 = *(const bf16x8*)&Xsb[(m0 + l16) * 40 + quad * 8];
  f32x4 c1[8];
#pragma unroll
  for (int t = 0; t < 8; ++t) {
    bf16x8 b =
        *(const bf16x8*)&w1b[(size_t)(f0 + t * 16 + l16) * 32 + quad * 8];
    f32x4 z = {0.f, 0.f, 0.f, 0.f};
    c1[t] = __builtin_amdgcn_mfma_f32_16x16x32_bf16(a1, b, z, 0, 0, 0);
  }
#pragma unroll
  for (int t = 0; t < 8; ++t) {
    float bb = b1[f0 + t * 16 + l16];
#pragma unroll
    for (int reg = 0; reg < 4; ++reg) {
      float v = fmaxf(c1[t][reg] + bb, 0.f);
      int rrow = m0 + quad * 4 + reg;
      Fsb[rrow * 136 + t * 16 + l16] = f2b(v);
    }
  }
  __syncthreads();

  f32x4 acc[2] = {{0.f, 0.f, 0.f, 0.f}, {0.f, 0.f, 0.f, 0.f}};
#pragma unroll
  for (int kt = 0; kt < 4; ++kt) {
    bf16x8 a2 = *(const bf16x8*)&Fsb[(m0 + l16) * 136 + kt * 32 + quad * 8];
#pragma unroll
    for (int u = 0; u < 2; ++u) {
      bf16x8 b =
          *(const bf16x8*)&w2b[(size_t)(u * 16 + l16) * FFD + f0 + kt * 32 + quad * 8];
      acc[u] = __builtin_amdgcn_mfma_f32_16x16x32_bf16(a2, b, acc[u], 0, 0, 0);
    }
  }
#pragma unroll
  for (int u = 0; u < 2; ++u) {
#pragma unroll
    for (int reg = 0; reg < 4; ++reg) {
      int rrow = r0 + m0 + quad * 4 + reg;
      if (rrow < LL)
        part2[((size_t)blockIdx.y * LL + rrow) * HDIM + u * 16 + l16] =
            acc[u][reg];
    }
  }
}

// ------ FFN part B: combine + residual + LN2 + next qkv (bf16) + final ------
__global__ __launch_bounds__(256) void k_ffnB_qkv(float* __restrict__ x,
    const float* __restrict__ part2, const float* __restrict__ b2,
    const float* __restrict__ g, const float* __restrict__ bln,
    const float* __restrict__ qw, const float* __restrict__ qb,
    unsigned short* __restrict__ Qb, unsigned short* __restrict__ KB,
    unsigned short* __restrict__ VBt, int do_qkv,
    const float* __restrict__ cw, const float* __restrict__ cb,
    float* __restrict__ out) {
  __shared__ float xs[8][33];
  int tid = threadIdx.x;
  int r = tid >> 5, ch = tid & 31;
  int row = blockIdx.x * 8 + r;
  bool ok = row < LL;
  float s = 0.f;
  if (ok) {
#pragma unroll
    for (int q = 0; q < NFS; ++q)
      s += part2[((size_t)q * LL + row) * HDIM + ch];
  }
  float val = ok ? (x[(size_t)row * HDIM + ch] + s + b2[ch]) : 0.f;
  float mean = val;
#pragma unroll
  for (int off = 16; off > 0; off >>= 1) mean += __shfl_xor(mean, off, 32);
  mean *= (1.f / 32.f);
  float d = val - mean;
  float var = d * d;
#pragma unroll
  for (int off = 16; off > 0; off >>= 1) var += __shfl_xor(var, off, 32);
  var *= (1.f / 32.f);
  float y = d / sqrtf(var + EPSLN) * g[ch] + bln[ch];
  if (ok) x[(size_t)row * HDIM + ch] = y;
  xs[r][ch] = ok ? y : 0.f;
  __syncthreads();
  if (!do_qkv) {
    if (blockIdx.x == 0 && r == 0) {
      float t = y * cw[ch];
#pragma unroll
      for (int off = 16; off > 0; off >>= 1) t += __shfl_xor(t, off, 32);
      if (ch == 0) {
        float z = t + cb[0];
        out[0] = 1.f / (1.f + expf(-z));
      }
    }
    return;
  }
  if (!ok) return;
#pragma unroll
  for (int t3 = 0; t3 < 3; ++t3) {
    int cc = t3 * 32 + ch;
    const float4* wr = (const float4*)(qw + (size_t)cc * HDIM);
    float acc = qb[cc];
#pragma unroll
    for (int k = 0; k < 8; ++k) {
      float4 wv = wr[k];
      acc = fmaf(xs[r][4 * k + 0], wv.x, acc);
      acc = fmaf(xs[r][4 * k + 1], wv.y, acc);
      acc = fmaf(xs[r][4 * k + 2], wv.z, acc);
      acc = fmaf(xs[r][4 * k + 3], wv.w, acc);
    }
    store_qkv_bf16(row, ch, t3, acc, Qb, KB, VBt);
  }
}

extern "C" void kernel_launch(void* const* d_in, const int* in_sizes, int n_in,
                              void* d_out, int out_size, void* d_ws, size_t ws_size,
                              hipStream_t stream) {
  const float* data  = (const float*)d_in[0];
  const float* lin_w = (const float*)d_in[1];
  const float* lin_b = (const float*)d_in[2];
  const float* qkv_w = (const float*)d_in[3];
  const float* qkv_b = (const float*)d_in[4];
  const float* out_w = (const float*)d_in[5];
  const float* out_b = (const float*)d_in[6];
  const float* ln1_g = (const float*)d_in[7];
  const float* ln1_b = (const float*)d_in[8];
  const float* ff1_w = (const float*)d_in[9];
  const float* ff1_b = (const float*)d_in[10];
  const float* ff2_w = (const float*)d_in[11];
  const float* ff2_b = (const float*)d_in[12];
  const float* ln2_g = (const float*)d_in[13];
  const float* ln2_b = (const float*)d_in[14];
  const float* cls_w = (const float*)d_in[15];
  const float* cls_b = (const float*)d_in[16];

  float* ws = (float*)d_ws;
  float* X = ws;                                       // LL*32 fp32
  unsigned short* Qb  = (unsigned short*)(X + (size_t)LL * 32);
  unsigned short* KB  = Qb + (size_t)QROWS * 32;       // 8*KPAD*32
  unsigned short* VBt = KB + (size_t)8 * KPAD * 32;    // 8*16*KPAD
  unsigned short* W1B = VBt + (size_t)8 * 16 * KPAD;   // NL*FFD*32
  unsigned short* W2B = W1B + (size_t)NLAYER * FFD * 32;
  float4* AP = (float4*)(W2B + (size_t)NLAYER * FFD * 32 + 32);
  // align AP to 16B
  AP = (float4*)(((size_t)AP + 15) & ~(size_t)15);
  float* LP = (float*)(AP + (size_t)NCHUNK * NHEAD * LL);
  float* PART2 = (float*)AP;                           // aliased lifetimes

  const int NROWB = (LL + 7) / 8;                      // 513
  const int NW = NLAYER * FFD * 32;                    // 393216
  const int NINIT = 8 * KPAD * 32;                     // largest init region

  k_init<<<(NINIT + 255) / 256, 256, 0, stream>>>(Qb, KB, VBt);
  k_wcvt<<<(NW + 255) / 256, 256, 0, stream>>>(ff1_w, ff2_w, W1B, W2B);
  k_embed_qkv<<<NROWB, 256, 0, stream>>>(data, lin_w, lin_b, X,
                                         qkv_w, qkv_b, Qb, KB, VBt);
  for (int l = 0; l < NLAYER; ++l) {
    k_attn<<<dim3(33, NHEAD, NCHUNK), 256, 0, stream>>>(Qb, KB, VBt, LP,
                                                        (float*)AP);
    k_oproj<<<NROWB, 256, 0, stream>>>(
        LP, AP, X, out_w + (size_t)l * 32 * 32, out_b + (size_t)l * 32,
        ln1_g + (size_t)l * 32, ln1_b + (size_t)l * 32);
    k_ffnA<<<dim3((LL + RT - 1) / RT, NFS), 256, 0, stream>>>(
        X, W1B + (size_t)l * FFD * 32, ff1_b + (size_t)l * FFD,
        W2B + (size_t)l * FFD * 32, PART2);
    int nl = l + 1;
    int do_qkv = (nl < NLAYER) ? 1 : 0;
    const float* qw = qkv_w + (size_t)(do_qkv ? nl : 0) * 96 * 32;
    const float* qb = qkv_b + (size_t)(do_qkv ? nl : 0) * 96;
    k_ffnB_qkv<<<NROWB, 256, 0, stream>>>(
        X, PART2, ff2_b + (size_t)l * 32,
        ln2_g + (size_t)l * 32, ln2_b + (size_t)l * 32,
        qw, qb, Qb, KB, VBt, do_qkv, cls_w, cls_b, (float*)d_out);
  }
}